// Round 6
// baseline (281.246 us; speedup 1.0000x reference)
//
#include <hip/hip_runtime.h>
#include <hip/hip_bf16.h>

typedef __bf16 bf16;
typedef __attribute__((ext_vector_type(8))) __bf16 bf16x8;
typedef __attribute__((ext_vector_type(4))) __bf16 bf16x4;
typedef __attribute__((ext_vector_type(4))) float f32x4;

#define M_TOK 32768   // B*S = 8*4096
#define D_    512
#define SCALE_ 0.125f

#define AS1 __attribute__((address_space(1)))
#define AS3 __attribute__((address_space(3)))

// ---------------- merged weight transpose+convert (one launch) ----------------
// bx < 48: W_qkv [512,1536] -> Wq_t [1536(perm),512] bf16.
//   Perm: col n = qkv*512 + h*64 + c  ->  row h*192 + (c>>4)*48 + qkv*16 + (c&15)
//   (per head: 4 groups of [q(16),k(16),v(16)] -> each wcol wave owns full q/k/v
//    triples for its 16 head-cols)
// bx >= 48: W_proj [512,512] -> Wp_t [512,512] bf16 (plain transpose)
__global__ __launch_bounds__(256) void transpose_cvt_all(const float* __restrict__ Wqkv,
                                                         const float* __restrict__ Wproj,
                                                         bf16* __restrict__ Wq_t,
                                                         bf16* __restrict__ Wp_t) {
  __shared__ float tile[32][33];
  const int bx = blockIdx.x;
  const float* in;
  bf16* out;
  int N, n0;
  bool perm;
  if (bx < 48) { in = Wqkv;  out = Wq_t; N = 1536; n0 = bx * 32;        perm = true;  }
  else         { in = Wproj; out = Wp_t; N = 512;  n0 = (bx - 48) * 32; perm = false; }
  const int k0 = blockIdx.y * 32;
  const int tx = threadIdx.x, ty = threadIdx.y;
  for (int i = 0; i < 32; i += 8)
    tile[ty + i][tx] = in[(size_t)(k0 + ty + i) * N + n0 + tx];
  __syncthreads();
  for (int i = 0; i < 32; i += 8) {
    int n = n0 + ty + i;
    int np = n;
    if (perm) {
      int qkv = n >> 9, h = (n & 511) >> 6, c = n & 63;
      np = h * 192 + (c >> 4) * 48 + qkv * 16 + (c & 15);
    }
    out[(size_t)np * D_ + k0 + tx] = (bf16)tile[tx][ty + i];
  }
}

// ---------------- single fused kernel: qkv GEMM + softmax + proj GEMM + resid ----
// Block = 64 tokens, 512 threads = 8 waves as 2 wrow x 4 wcol.
// LDS: sX 64KB = x-tile [64][512] bf16 (staged ONCE, serves all 8 heads; retired
//      after qkv -> becomes O storage). sY 64KB = qkv-B dbuf (2x24KB) -> proj-Wp
//      dbuf (2x32KB). sS 1KB softmax partial sums. 129 KB total, 1 block/CU.
// qkv phase: per head h, wave tile 32 rows x 48 B-rows (acc[2][3] = q,k,v for
//   head-col wcol*16+fr). 64 K-tiles streamed (8 heads x 8), B-only staging
//   (3 gload_lds/tile), dbuf + counted vmcnt(3), raw barriers (never drain).
// softmax: NO max-subtraction (scores ~N(0,0.08); softmax shift-invariant, exp
//   safe in fp32). Per-wave 16-lane shfl sum; 4-wave merge via one f32x4 read.
//   O kept in regs: bf16x4 opk[8][2] (32 VGPR). O never touches HBM.
// proj phase: O regs -> sX (swizzled), Wp dbuf BK=32 in sY, out 64x512 in regs
//   (pacc[2][8]); epilogue adds bproj + fp32 residual re-read of x.
// Swizzle invariant everywhere: LDS[row][slot] = logical[row][slot_low ^ (row&mask)].
__global__ __launch_bounds__(512, 2) void fused_attn(const float* __restrict__ x,
                                                     const bf16* __restrict__ Wq_t,
                                                     const float* __restrict__ bqkv,
                                                     const bf16* __restrict__ Wp_t,
                                                     const float* __restrict__ bproj,
                                                     float* __restrict__ out) {
  __shared__ __align__(16) bf16 sX[64 * 512];      // 64 KB
  __shared__ __align__(16) bf16 sY[2][512 * 32];   // 64 KB (qkv uses 24KB/half)
  __shared__ __align__(16) float sS[64 * 4];       // 1 KB

  const int tid = threadIdx.x;
  const int w = tid >> 6, l = tid & 63;
  const int wrow = w >> 2, wcol = w & 3;
  const int m0 = blockIdx.x * 64;
  const int fr = l & 15, fkc = l >> 4, frs = fr & 7;
  const int rbase = fkc * 4;

  // ---- stage x-tile once: fp32 -> bf16, 8-chunk XOR swizzle ----
#pragma unroll
  for (int q = 0; q < 8; ++q) {
    int u = tid + 512 * q;
    int row = u >> 6, slot = u & 63;
    int gch = (slot & 56) | ((slot & 7) ^ (row & 7));
    const float* gp = x + (size_t)(m0 + row) * D_ + gch * 8;
    f32x4 a = *(const f32x4*)gp;
    f32x4 b = *(const f32x4*)(gp + 4);
    bf16x8 v;
#pragma unroll
    for (int e = 0; e < 4; ++e) { v[e] = (bf16)a[e]; v[4 + e] = (bf16)b[e]; }
    *(bf16x8*)&sX[row * 512 + slot * 8] = v;
  }

  // ---- qkv B staging: [192][64] per K-tile, 3 x 16B units/thread ----
  const int bsrow = tid >> 3;                    // 0..63 (+64q)
  const int bgch  = (tid & 7) ^ (bsrow & 7);
  auto stageB = [&](int buf, int T) {
    const int hh = T >> 3, tt = T & 7;
#pragma unroll
    for (int q = 0; q < 3; ++q) {
      int row = 64 * q + bsrow;
      const bf16* gp = Wq_t + (size_t)(hh * 192 + row) * D_ + tt * 64 + bgch * 8;
      __builtin_amdgcn_global_load_lds((AS1 const void*)gp,
                                       (AS3 void*)&sY[buf][4096 * q + w * 512], 16, 0, 0);
    }
  };

  f32x4 acc[2][3];
  auto qkvK = [&](int buf, int tt, int kk) {
    const int cb = tt * 8 + kk * 4 + fkc;        // x chunk 0..63
    const int xslot = (cb & 56) | ((cb & 7) ^ frs);
    bf16x8 af[2], bfr[3];
#pragma unroll
    for (int i = 0; i < 2; ++i)
      af[i] = *(const bf16x8*)&sX[(wrow * 32 + i * 16 + fr) * 512 + xslot * 8];
    const int c2 = kk * 4 + fkc;                 // B chunk 0..7 (row&7 == frs)
#pragma unroll
    for (int j = 0; j < 3; ++j)
      bfr[j] = *(const bf16x8*)&sY[buf][(wcol * 48 + j * 16 + fr) * 64 + (c2 ^ frs) * 8];
    __builtin_amdgcn_s_setprio(1);
#pragma unroll
    for (int i = 0; i < 2; ++i)
#pragma unroll
      for (int j = 0; j < 3; ++j)
        acc[i][j] = __builtin_amdgcn_mfma_f32_16x16x32_bf16(af[i], bfr[j], acc[i][j], 0, 0, 0);
    __builtin_amdgcn_s_setprio(0);
  };

  bf16x4 opk[8][2];                              // O in regs (h, i statically indexed)

  // prologue: B(0) in flight (x-loads older, drained by first vmcnt(3))
  stageB(0, 0);
  asm volatile("s_waitcnt lgkmcnt(0)" ::: "memory");   // x-tile ds_writes done

#pragma unroll
  for (int h = 0; h < 8; ++h) {
#pragma unroll
    for (int i = 0; i < 2; ++i)
#pragma unroll
      for (int j = 0; j < 3; ++j) {
        f32x4 z = {0.f, 0.f, 0.f, 0.f};
        acc[i][j] = z;
      }
#pragma unroll 2
    for (int t = 0; t < 8; ++t) {
      const int T = h * 8 + t;
      const int buf = t & 1;
      if (T < 63) {
        stageB(buf ^ 1, T + 1);                  // 3 loads fly across barriers
        asm volatile("s_waitcnt vmcnt(3)" ::: "memory");   // tile T staged
      } else {
        asm volatile("s_waitcnt vmcnt(0)" ::: "memory");
      }
      __builtin_amdgcn_s_barrier();
      qkvK(buf, t, 0);
      qkvK(buf, t, 1);
      if (t == 7) {
        // ---- softmax head h (no max-sub; raw barrier, prefetch stays in flight) ----
        const int hcol = h * 64 + wcol * 16 + fr;
        const float bq = bqkv[hcol];
        const float bk = bqkv[512 + hcol];
        const float bv = bqkv[1024 + hcol];
        float ev[2][4];
#pragma unroll
        for (int i = 0; i < 2; ++i)
#pragma unroll
          for (int r = 0; r < 4; ++r) {
            float e = __expf((acc[i][0][r] + bq - acc[i][1][r] - bk) * SCALE_);
            ev[i][r] = e;
            float sm = e;
#pragma unroll
            for (int off = 1; off < 16; off <<= 1) sm += __shfl_xor(sm, off);
            if (fr == 0)
              sS[(wrow * 32 + i * 16 + rbase + r) * 4 + wcol] = sm;
          }
        asm volatile("s_waitcnt lgkmcnt(0)" ::: "memory");
        __builtin_amdgcn_s_barrier();
#pragma unroll
        for (int i = 0; i < 2; ++i) {
          bf16x4 p;
#pragma unroll
          for (int r = 0; r < 4; ++r) {
            f32x4 sv = *(const f32x4*)&sS[(wrow * 32 + i * 16 + rbase + r) * 4];
            float tot = (sv[0] + sv[1]) + (sv[2] + sv[3]);
            p[r] = (bf16)(ev[i][r] / tot * (acc[i][2][r] + bv));
          }
          opk[h][i] = p;
        }
      }
      __builtin_amdgcn_s_barrier();
    }
  }

  // ---- transition: x-tile dead -> write O into sX; stage Wp(0) ----
  const int psrow = tid >> 2;                    // 0..127 (+128q)
  const int pgch  = (tid & 3) ^ (psrow & 3);
  auto stageP = [&](int buf, int tk) {
#pragma unroll
    for (int q = 0; q < 4; ++q) {
      int row = 128 * q + psrow;
      const bf16* gp = Wp_t + (size_t)row * D_ + tk * 32 + pgch * 8;
      __builtin_amdgcn_global_load_lds((AS1 const void*)gp,
                                       (AS3 void*)&sY[buf][4096 * q + w * 512], 16, 0, 0);
    }
  };
  stageP(0, 0);                                  // issue first (overlaps O writes)
#pragma unroll
  for (int h = 0; h < 8; ++h)
#pragma unroll
    for (int i = 0; i < 2; ++i)
#pragma unroll
      for (int r = 0; r < 4; ++r) {
        int row = wrow * 32 + i * 16 + rbase + r;
        int col = h * 64 + wcol * 16 + fr;
        int c = col >> 3;
        int slot = (c & 56) | ((c & 7) ^ (row & 7));
        sX[row * 512 + slot * 8 + (col & 7)] = opk[h][i][r];
      }
  asm volatile("s_waitcnt lgkmcnt(0)" ::: "memory");
  __builtin_amdgcn_s_barrier();

  // ---- proj GEMM: out[64][512] += O @ Wp^T, BK=32, 16 K-tiles ----
  f32x4 pacc[2][8];
#pragma unroll
  for (int i = 0; i < 2; ++i)
#pragma unroll
    for (int j = 0; j < 8; ++j) {
      f32x4 z = {0.f, 0.f, 0.f, 0.f};
      pacc[i][j] = z;
    }

#pragma unroll 2
  for (int tk = 0; tk < 16; ++tk) {
    const int buf = tk & 1;
    if (tk < 15) {
      stageP(buf ^ 1, tk + 1);
      asm volatile("s_waitcnt vmcnt(4)" ::: "memory");   // tile tk staged
    } else {
      asm volatile("s_waitcnt vmcnt(0)" ::: "memory");
    }
    __builtin_amdgcn_s_barrier();
    const int cg = tk * 4 + fkc;                 // O chunk 0..63
    const int xslot = (cg & 56) | ((cg & 7) ^ frs);
    bf16x8 paf[2], pbf[8];
#pragma unroll
    for (int i = 0; i < 2; ++i)
      paf[i] = *(const bf16x8*)&sX[(wrow * 32 + i * 16 + fr) * 512 + xslot * 8];
#pragma unroll
    for (int j = 0; j < 8; ++j) {
      int row = wcol * 128 + j * 16 + fr;        // row&3 == fr&3
      pbf[j] = *(const bf16x8*)&sY[buf][row * 32 + (fkc ^ (fr & 3)) * 8];
    }
    __builtin_amdgcn_s_setprio(1);
#pragma unroll
    for (int i = 0; i < 2; ++i)
#pragma unroll
      for (int j = 0; j < 8; ++j)
        pacc[i][j] = __builtin_amdgcn_mfma_f32_16x16x32_bf16(paf[i], pbf[j], pacc[i][j], 0, 0, 0);
    __builtin_amdgcn_s_setprio(0);
    __builtin_amdgcn_s_barrier();
  }

  // ---- epilogue: + bias + residual (fp32 x re-read), fp32 out ----
#pragma unroll
  for (int j = 0; j < 8; ++j) {
    int n = wcol * 128 + j * 16 + fr;
    float bb = bproj[n];
#pragma unroll
    for (int i = 0; i < 2; ++i)
#pragma unroll
      for (int r = 0; r < 4; ++r) {
        int m = m0 + wrow * 32 + i * 16 + rbase + r;
        out[(size_t)m * D_ + n] = pacc[i][j][r] + bb + x[(size_t)m * D_ + n];
      }
  }
}

extern "C" void kernel_launch(void* const* d_in, const int* in_sizes, int n_in,
                              void* d_out, int out_size, void* d_ws, size_t ws_size,
                              hipStream_t stream) {
  const float* x     = (const float*)d_in[0];   // [32768, 512]
  const float* Wqkv  = (const float*)d_in[1];   // [512, 1536]
  const float* bqkv  = (const float*)d_in[2];   // [1536]
  const float* Wproj = (const float*)d_in[3];   // [512, 512]
  const float* bproj = (const float*)d_in[4];   // [512]
  float* out = (float*)d_out;

  // workspace (~2.1 MB): only transposed weights; no Xb, no O
  char* ws = (char*)d_ws;
  bf16* Wq_t = (bf16*)ws;                               // [1536,512] perm
  bf16* Wp_t = (bf16*)(ws + (size_t)1536 * D_ * 2);     // [512,512]

  transpose_cvt_all<<<dim3(64, 16), dim3(32, 8), 0, stream>>>(Wqkv, Wproj, Wq_t, Wp_t);

  fused_attn<<<dim3(M_TOK / 64), dim3(512), 0, stream>>>(x, Wq_t, bqkv, Wp_t, bproj, out);
}